// Round 11
// baseline (61.185 us; speedup 1.0000x reference)
//
#include <hip/hip_runtime.h>
#include <hip/hip_bf16.h>

// x: [4, 4096, 4096] f32, W1: [48, 4096] f32, W2: [48, 48] f32
// out: [4, 4, 4096, 12] f32  (C, B, T, L/C)
#define DDIM 4096
#define LTOT 48

typedef __attribute__((ext_vector_type(4))) float f32x4;
typedef __attribute__((ext_vector_type(8))) short bf16x8;

__device__ __forceinline__ void gload_lds16(const void* g, void* l) {
    __builtin_amdgcn_global_load_lds(
        (const __attribute__((address_space(1))) void*)g,
        (__attribute__((address_space(3))) void*)l, 16, 0, 0);
}

__device__ __forceinline__ unsigned cvt_pk(float x, float y) {
    union { __hip_bfloat162 h; unsigned u; } c;
    c.h = __float22bfloat162_rn(make_float2(x, y));
    return c.u;
}

// ---- kernel 0: W1 fp32 -> bf16 (RNE) into workspace ----
__global__ void w1cvt_kernel(const float* __restrict__ w1, ushort* __restrict__ w1b) {
    int i = blockIdx.x * 256 + threadIdx.x;
    union { float f; unsigned u; } v; v.f = w1[i];
    unsigned r = v.u + 0x7fffu + ((v.u >> 16) & 1u);
    w1b[i] = (ushort)(r >> 16);
}

// ---- fused: 64-row blocks (4 MFMA row-tiles/wave), 4-wave K-split,
//      DMA-staged double buffer; quarters W1b L2 traffic vs 16-row ----
__global__ __launch_bounds__(256, 1) void fused_kernel(
        const float* __restrict__ x,
        const ushort* __restrict__ w1b,
        const float* __restrict__ w2,
        float* __restrict__ out) {
    // staging: 4 waves x 2 buffers x 16384B (64 rows x 64 f32, XOR-swizzled)
    __shared__ __align__(1024) char smem[131072];
    __shared__ float ssw[4][64];
    __shared__ float scl[64];

    const int tid  = threadIdx.x;
    const int wave = tid >> 6;
    const int lane = tid & 63;
    const int rl   = lane & 15;   // A-row (within tile) / B-row / C-col
    const int kg   = lane >> 4;   // k-group 0..3
    const int row0 = blockIdx.x * 64;
    const int kw   = wave * 1024; // per-wave K range
    const int rot  = blockIdx.x & 15;

    char* wbase = smem + wave * 32768;

    // ds_read offsets for (tile T, half h, piece p): row r = T*16+rl,
    // logical 16B-block g = h*8+kg*2+p stored at LDS pos g ^ rl of row r
    int dso[4][2][2];
    #pragma unroll
    for (int T = 0; T < 4; ++T)
        #pragma unroll
        for (int h = 0; h < 2; ++h)
            #pragma unroll
            for (int p = 0; p < 2; ++p)
                dso[T][h][p] = (T * 16 + rl) * 256 + (((h * 8 + kg * 2 + p) ^ rl) << 4);

    // stage pipeline-step t into buffer t&1: 16 x 1KB DMA (rows i*4+kg),
    // linear LDS dest, inverse-swizzled per-lane global source
    auto stage = [&](int t) {
        const int kb = kw + ((t + rot) & 15) * 64;
        char* lb = wbase + (t & 1) * 16384;
        #pragma unroll
        for (int i = 0; i < 16; ++i) {
            int r    = i * 4 + kg;           // row this lane's 16B lands in
            int blkg = rl ^ (r & 15);        // source block (inverse swizzle)
            const float* src = x + (size_t)(row0 + r) * DDIM + kb + blkg * 4;
            gload_lds16(src, lb + i * 1024);
        }
    };

    // B fragments for pipeline-step s (6 x 16B, L2-resident)
    auto loadB = [&](int s, bf16x8 (&bl)[6]) {
        const ushort* bp = w1b + (size_t)rl * DDIM + kw + ((s + rot) & 15) * 64 + kg * 8;
        #pragma unroll
        for (int n = 0; n < 3; ++n)
            #pragma unroll
            for (int h = 0; h < 2; ++h)
                bl[n * 2 + h] = *(const bf16x8*)(bp + n * 16 * DDIM + h * 32);
    };

    float ss[4] = {0.f, 0.f, 0.f, 0.f};
    f32x4 acc[4][3];
    #pragma unroll
    for (int T = 0; T < 4; ++T)
        #pragma unroll
        for (int n = 0; n < 3; ++n)
            acc[T][n] = (f32x4){0.f, 0.f, 0.f, 0.f};
    bf16x8 bA[6], bB[6];

    // prologue: B0 issued BETWEEN the two stages so no wait ever drains stage(1)
    stage(0); loadB(0, bA); stage(1);

    auto body = [&](int s, bf16x8 (&bu)[6], bf16x8 (&bl)[6]) {
        // retire exactly stage(s)+B(s): queue [st(s):16][B(s):6][st(s+1):16]
        if (s == 0)       asm volatile("s_waitcnt vmcnt(22)" ::: "memory");
        else if (s == 15) asm volatile("s_waitcnt vmcnt(6)"  ::: "memory"); // [st15:16][B15:6]
        else              asm volatile("s_waitcnt vmcnt(16)" ::: "memory");
        char* lb = wbase + (s & 1) * 16384;
        if (s < 15) loadB(s + 1, bl);   // B one step ahead (reg double-buffer)

        #pragma unroll
        for (int T = 0; T < 4; ++T) {
            f32x4 a[2][2];
            #pragma unroll
            for (int h = 0; h < 2; ++h)
                #pragma unroll
                for (int p = 0; p < 2; ++p)
                    a[h][p] = *(const f32x4*)(lb + dso[T][h][p]);
            #pragma unroll
            for (int h = 0; h < 2; ++h) {
                f32x4 a0 = a[h][0], a1 = a[h][1];
                ss[T] = fmaf(a0.x, a0.x, ss[T]); ss[T] = fmaf(a0.y, a0.y, ss[T]);
                ss[T] = fmaf(a0.z, a0.z, ss[T]); ss[T] = fmaf(a0.w, a0.w, ss[T]);
                ss[T] = fmaf(a1.x, a1.x, ss[T]); ss[T] = fmaf(a1.y, a1.y, ss[T]);
                ss[T] = fmaf(a1.z, a1.z, ss[T]); ss[T] = fmaf(a1.w, a1.w, ss[T]);
                union { bf16x8 v; unsigned u[4]; } af;
                af.u[0] = cvt_pk(a0.x, a0.y); af.u[1] = cvt_pk(a0.z, a0.w);
                af.u[2] = cvt_pk(a1.x, a1.y); af.u[3] = cvt_pk(a1.z, a1.w);
                #pragma unroll
                for (int n = 0; n < 3; ++n)
                    acc[T][n] = __builtin_amdgcn_mfma_f32_16x16x32_bf16(
                                    af.v, bu[n * 2 + h], acc[T][n], 0, 0, 0);
            }
        }
        // ds_reads of this buffer must land before we overwrite it
        asm volatile("s_waitcnt lgkmcnt(0)" ::: "memory");
        if (s < 14) stage(s + 2);
    };

    for (int sp = 0; sp < 8; ++sp) {
        body(2 * sp,     bA, bB);
        body(2 * sp + 1, bB, bA);
    }

    // ---- reductions ----
    #pragma unroll
    for (int T = 0; T < 4; ++T) {
        float v = ss[T];
        v += __shfl_xor(v, 16);
        v += __shfl_xor(v, 32);
        if (lane < 16) ssw[wave][T * 16 + lane] = v;
    }

    asm volatile("s_waitcnt vmcnt(0) lgkmcnt(0)" ::: "memory");
    __syncthreads();   // staging LDS free -> overlay epilogue arrays

    float* dots = (float*)smem;             // [4][64][48] = 49152 B
    float* gbuf = (float*)(smem + 49152);   // [64][48]    = 12288 B
    float* w2s  = (float*)(smem + 61440);   // [48][48]    =  9216 B

    #pragma unroll
    for (int T = 0; T < 4; ++T)
        #pragma unroll
        for (int n = 0; n < 3; ++n)
            #pragma unroll
            for (int i = 0; i < 4; ++i)
                dots[(wave * 64 + T * 16 + kg * 4 + i) * 48 + n * 16 + rl] = acc[T][n][i];
    for (int i = tid; i < LTOT * LTOT; i += 256) w2s[i] = w2[i];
    if (tid < 64) {
        float st = ssw[0][tid] + ssw[1][tid] + ssw[2][tid] + ssw[3][tid];
        scl[tid] = rsqrtf(st * (1.0f / (float)DDIM) + 1e-5f);
    }
    __syncthreads();

    #pragma unroll
    for (int i = 0; i < 12; ++i) {
        int v = tid + i * 256;                 // 0..3071 = 64*48
        int row = v / 48, col = v - row * 48;
        float d = dots[(0 * 64 + row) * 48 + col] + dots[(1 * 64 + row) * 48 + col]
                + dots[(2 * 64 + row) * 48 + col] + dots[(3 * 64 + row) * 48 + col];
        float h = d * scl[row];
        gbuf[row * 48 + col] = h * 0.5f * (1.0f + erff(h * 0.70710678118654752f));
    }
    __syncthreads();

    #pragma unroll
    for (int i = 0; i < 12; ++i) {
        int v = tid + i * 256;
        int row = v / 48, l = v - row * 48;
        float sacc = 0.f;
        #pragma unroll
        for (int k = 0; k < LTOT; ++k)
            sacc = fmaf(gbuf[row * 48 + k], w2s[l * LTOT + k], sacc);
        int rg = row0 + row;
        int b  = rg >> 12;
        int t  = rg & 4095;
        int c  = l / 12, j = l - c * 12;
        out[(((size_t)(c * 4 + b) * 4096 + t) * 12) + j] = sacc;
    }
}

extern "C" void kernel_launch(void* const* d_in, const int* in_sizes, int n_in,
                              void* d_out, int out_size, void* d_ws, size_t ws_size,
                              hipStream_t stream) {
    const float* x  = (const float*)d_in[0];
    const float* W1 = (const float*)d_in[1];
    const float* W2 = (const float*)d_in[2];
    float* out = (float*)d_out;
    ushort* w1b = (ushort*)d_ws;

    w1cvt_kernel<<<(LTOT * DDIM) / 256, 256, 0, stream>>>(W1, w1b);
    fused_kernel<<<16384 / 64, 256, 0, stream>>>(x, w1b, W2, out);
}